// Round 1
// baseline (510.341 us; speedup 1.0000x reference)
//
#include <hip/hip_runtime.h>

// AttnBlock: b=2, c=256, n=4096 (16^3), G=32 groups.
// d_out = [ out0: (2,256,4096) fp32 | attn: (2,4096,4096) fp32 (P^T) ]
// All GEMMs are TN (A=[M][K], B=[N][K], K contiguous) with bf16 MFMA 16x16x32.

typedef __bf16 bf16_t;
typedef __bf16 bf16x8 __attribute__((ext_vector_type(8)));
typedef float floatx4 __attribute__((ext_vector_type(4)));

__device__ __forceinline__ unsigned short f2bf(float f) {
  union { float f; unsigned int u; } v; v.f = f;
  return (unsigned short)((v.u + 0x7FFFu + ((v.u >> 16) & 1u)) >> 16);
}

// ---------------- weight fp32 -> bf16 convert (wq,wk,wv,wp) ----------------
__global__ void conv_w_kernel(const float* __restrict__ w0, const float* __restrict__ w1,
                              const float* __restrict__ w2, const float* __restrict__ w3,
                              unsigned short* __restrict__ dst) {
  const float* src = (blockIdx.z == 0) ? w0 : (blockIdx.z == 1) ? w1 : (blockIdx.z == 2) ? w2 : w3;
  int i = blockIdx.x * 256 + threadIdx.x;
  dst[(size_t)blockIdx.z * 65536 + i] = f2bf(src[i]);
}

// ---------------- GroupNorm stats: one block per (b,g), 8*4096 contiguous floats ----
__global__ void gn_stats_kernel(const float* __restrict__ x, float* __restrict__ mean,
                                float* __restrict__ rstd) {
  int bg = blockIdx.x;  // b*32+g
  const float* p = x + (size_t)bg * 32768;
  float s = 0.f, ss = 0.f;
  for (int i = threadIdx.x * 4; i < 32768; i += 1024) {
    float4 v = *(const float4*)&p[i];
    s += v.x + v.y + v.z + v.w;
    ss += v.x * v.x + v.y * v.y + v.z * v.z + v.w * v.w;
  }
  for (int off = 32; off > 0; off >>= 1) {
    s += __shfl_down(s, off);
    ss += __shfl_down(ss, off);
  }
  __shared__ float bs[4], bss[4];
  int wid = threadIdx.x >> 6;
  if ((threadIdx.x & 63) == 0) { bs[wid] = s; bss[wid] = ss; }
  __syncthreads();
  if (threadIdx.x == 0) {
    float S = bs[0] + bs[1] + bs[2] + bs[3];
    float SS = bss[0] + bss[1] + bss[2] + bss[3];
    float mu = S * (1.f / 32768.f);
    float var = SS * (1.f / 32768.f) - mu * mu;
    mean[bg] = mu;
    rstd[bg] = rsqrtf(var + 1e-6f);
  }
}

// ---------------- GroupNorm apply + transpose: write hnT[b][n][c] bf16 --------------
__global__ void gn_apply_t_kernel(const float* __restrict__ x, const float* __restrict__ gamma,
                                  const float* __restrict__ beta, const float* __restrict__ mean,
                                  const float* __restrict__ rstd, unsigned short* __restrict__ hnT) {
  int n0 = blockIdx.x * 64, c0 = blockIdx.y * 64, b = blockIdx.z;
  int tid = threadIdx.x;
  __shared__ __align__(16) unsigned short T[64 * 72];
#pragma unroll
  for (int r = 0; r < 4; ++r) {
    int cl = (tid >> 4) + r * 16;
    int nl = (tid & 15) * 4;
    int c = c0 + cl;
    int bg = b * 32 + (c >> 3);
    float mu = mean[bg], rs = rstd[bg], ga = gamma[c], be = beta[c];
    float4 v = *(const float4*)&x[(size_t)b * 1048576 + (size_t)c * 4096 + n0 + nl];
    ushort4 u;
    u.x = f2bf((v.x - mu) * rs * ga + be);
    u.y = f2bf((v.y - mu) * rs * ga + be);
    u.z = f2bf((v.z - mu) * rs * ga + be);
    u.w = f2bf((v.w - mu) * rs * ga + be);
    *(ushort4*)&T[cl * 72 + nl] = u;
  }
  __syncthreads();
#pragma unroll
  for (int w = 0; w < 2; ++w) {
    int nl = (tid >> 3) + w * 32;
    int cch = (tid & 7) * 8;
    unsigned short u8[8];
#pragma unroll
    for (int i = 0; i < 8; ++i) u8[i] = T[(cch + i) * 72 + nl];
    size_t o = (size_t)b * 1048576 + (size_t)(n0 + nl) * 256 + c0 + cch;
    *(ushort4*)&hnT[o] = make_ushort4(u8[0], u8[1], u8[2], u8[3]);
    *(ushort4*)&hnT[o + 4] = make_ushort4(u8[4], u8[5], u8[6], u8[7]);
  }
}

// ---------------- Generic TN bf16 MFMA GEMM --------------------------------
// C[m][n] = scale * sum_k A[m][k]*B[n][k]  (+bias[m]) (+resid)
// MODE 0: fp32 natural store. MODE 1: fp32 natural + bias + residual.
// MODE 2: bf16 natural store (+bias). MODE 3: bf16 transposed store CT[n*M+m] (+bias).
template <int BM, int BN, int MODE>
__launch_bounds__(256)
__global__ void gemm_tn(const bf16_t* __restrict__ A0, long long sA,
                        const bf16_t* __restrict__ B0, long long sB,
                        void* __restrict__ C0, long long sC,
                        const float* __restrict__ bias,
                        const float* __restrict__ resid, long long sR,
                        float scale, int M, int N, int K) {
  constexpr int BK = 32, LD = BK + 8;
  constexpr int WM = BM / 2, WN = BN / 2, MI = WM / 16, NI = WN / 16;
  __shared__ __align__(16) bf16_t As[BM * LD];
  __shared__ __align__(16) bf16_t Bs[BN * LD];
  const int tid = threadIdx.x;
  const int lane = tid & 63, wid = tid >> 6;
  const int quad = lane >> 4, l16 = lane & 15;
  const int bz = blockIdx.z;
  const bf16_t* A = A0 + (size_t)bz * sA;
  const bf16_t* B = B0 + (size_t)bz * sB;
  const int m0 = blockIdx.y * BM, n0 = blockIdx.x * BN;
  const int wm0 = (wid >> 1) * WM, wn0 = (wid & 1) * WN;

  floatx4 acc[MI][NI];
#pragma unroll
  for (int i = 0; i < MI; ++i)
#pragma unroll
    for (int j = 0; j < NI; ++j) acc[i][j] = (floatx4){0.f, 0.f, 0.f, 0.f};

  const int arow = tid >> 2, akj = (tid & 3) << 3;
  for (int kt = 0; kt < K; kt += BK) {
#pragma unroll
    for (int p = 0; p < BM / 64; ++p) {
      int r = p * 64 + arow;
      *(uint4*)&As[r * LD + akj] = *(const uint4*)&A[(size_t)(m0 + r) * K + kt + akj];
    }
#pragma unroll
    for (int p = 0; p < BN / 64; ++p) {
      int r = p * 64 + arow;
      *(uint4*)&Bs[r * LD + akj] = *(const uint4*)&B[(size_t)(n0 + r) * K + kt + akj];
    }
    __syncthreads();
    bf16x8 af[MI], bfr[NI];
#pragma unroll
    for (int i = 0; i < MI; ++i) af[i] = *(const bf16x8*)&As[(wm0 + i * 16 + l16) * LD + quad * 8];
#pragma unroll
    for (int j = 0; j < NI; ++j) bfr[j] = *(const bf16x8*)&Bs[(wn0 + j * 16 + l16) * LD + quad * 8];
#pragma unroll
    for (int i = 0; i < MI; ++i)
#pragma unroll
      for (int j = 0; j < NI; ++j)
        acc[i][j] = __builtin_amdgcn_mfma_f32_16x16x32_bf16(af[i], bfr[j], acc[i][j], 0, 0, 0);
    __syncthreads();
  }

#pragma unroll
  for (int i = 0; i < MI; ++i) {
    int gmb = m0 + wm0 + i * 16 + quad * 4;  // base row, 4 consecutive rows r=0..3
#pragma unroll
    for (int j = 0; j < NI; ++j) {
      int gn = n0 + wn0 + j * 16 + l16;
      float v[4];
#pragma unroll
      for (int r = 0; r < 4; ++r) v[r] = acc[i][j][r] * scale;
      if (MODE != 0 && bias != nullptr) {
#pragma unroll
        for (int r = 0; r < 4; ++r) v[r] += bias[gmb + r];
      }
      if (MODE == 0 || MODE == 1) {
        float* Cf = (float*)C0 + (size_t)bz * sC;
        if (MODE == 1 && resid != nullptr) {
#pragma unroll
          for (int r = 0; r < 4; ++r)
            v[r] += resid[(size_t)bz * sR + (size_t)(gmb + r) * N + gn];
        }
#pragma unroll
        for (int r = 0; r < 4; ++r) Cf[(size_t)(gmb + r) * N + gn] = v[r];
      } else if (MODE == 2) {
        unsigned short* Cb = (unsigned short*)C0 + (size_t)bz * sC;
#pragma unroll
        for (int r = 0; r < 4; ++r) Cb[(size_t)(gmb + r) * N + gn] = f2bf(v[r]);
      } else {  // MODE 3: transposed bf16 store, 4 contiguous M-elements packed
        unsigned short* Cb = (unsigned short*)C0 + (size_t)bz * sC;
        ushort4 u = make_ushort4(f2bf(v[0]), f2bf(v[1]), f2bf(v[2]), f2bf(v[3]));
        *(ushort4*)&Cb[(size_t)gn * M + gmb] = u;
      }
    }
  }
}

// ---------------- softmax over columns of S^T (axis m = rows of S^T) --------
__global__ void softmax_part_kernel(const float* __restrict__ ST, float* __restrict__ pmax,
                                    float* __restrict__ psum) {
  int b = blockIdx.z, mc = blockIdx.y;
  int n = blockIdx.x * 256 + threadIdx.x;
  const float* S = ST + (size_t)b * 16777216 + n;
  float mx = -1e30f, s = 0.f;
  int m0 = mc * 512;
  for (int m = m0; m < m0 + 512; ++m) {
    float v = S[(size_t)m * 4096];
    if (v > mx) {
      s = s * __expf(mx - v) + 1.f;
      mx = v;
    } else {
      s += __expf(v - mx);
    }
  }
  pmax[(size_t)(b * 8 + mc) * 4096 + n] = mx;
  psum[(size_t)(b * 8 + mc) * 4096 + n] = s;
}

__global__ void softmax_comb_kernel(const float* __restrict__ pmax, const float* __restrict__ psum,
                                    float* __restrict__ gmax, float* __restrict__ grsum) {
  int b = blockIdx.y;
  int n = blockIdx.x * 256 + threadIdx.x;
  float mx = -1e30f;
#pragma unroll
  for (int mc = 0; mc < 8; ++mc) mx = fmaxf(mx, pmax[(size_t)(b * 8 + mc) * 4096 + n]);
  float s = 0.f;
#pragma unroll
  for (int mc = 0; mc < 8; ++mc)
    s += psum[(size_t)(b * 8 + mc) * 4096 + n] * __expf(pmax[(size_t)(b * 8 + mc) * 4096 + n] - mx);
  gmax[b * 4096 + n] = mx;
  grsum[b * 4096 + n] = 1.f / s;
}

// normalize S^T -> P^T fp32 in place (d_out) + write transposed bf16 P[n][m] for PV
__global__ void softmax_norm_t_kernel(float* __restrict__ ST, const float* __restrict__ gmax,
                                      const float* __restrict__ grsum,
                                      unsigned short* __restrict__ P) {
  int m0 = blockIdx.x * 64, n0 = blockIdx.y * 64, b = blockIdx.z;
  int tid = threadIdx.x;
  __shared__ float gmx[64], grs[64];
  __shared__ __align__(16) unsigned short T[64 * 72];
  if (tid < 64) {
    gmx[tid] = gmax[b * 4096 + n0 + tid];
    grs[tid] = grsum[b * 4096 + n0 + tid];
  }
  __syncthreads();
#pragma unroll
  for (int r = 0; r < 4; ++r) {
    int ml = (tid >> 4) + r * 16;
    int nl = (tid & 15) * 4;
    size_t idx = (size_t)b * 16777216 + (size_t)(m0 + ml) * 4096 + n0 + nl;
    float4 s = *(float4*)&ST[idx];
    float4 p;
    p.x = __expf(s.x - gmx[nl + 0]) * grs[nl + 0];
    p.y = __expf(s.y - gmx[nl + 1]) * grs[nl + 1];
    p.z = __expf(s.z - gmx[nl + 2]) * grs[nl + 2];
    p.w = __expf(s.w - gmx[nl + 3]) * grs[nl + 3];
    *(float4*)&ST[idx] = p;
    *(ushort4*)&T[ml * 72 + nl] = make_ushort4(f2bf(p.x), f2bf(p.y), f2bf(p.z), f2bf(p.w));
  }
  __syncthreads();
#pragma unroll
  for (int w = 0; w < 2; ++w) {
    int nl = (tid >> 3) + w * 32;
    int mch = (tid & 7) * 8;
    unsigned short u8[8];
#pragma unroll
    for (int i = 0; i < 8; ++i) u8[i] = T[(mch + i) * 72 + nl];
    size_t o = (size_t)b * 16777216 + (size_t)(n0 + nl) * 4096 + m0 + mch;
    *(ushort4*)&P[o] = make_ushort4(u8[0], u8[1], u8[2], u8[3]);
    *(ushort4*)&P[o + 4] = make_ushort4(u8[4], u8[5], u8[6], u8[7]);
  }
}

extern "C" void kernel_launch(void* const* d_in, const int* in_sizes, int n_in,
                              void* d_out, int out_size, void* d_ws, size_t ws_size,
                              hipStream_t stream) {
  const float* x = (const float*)d_in[0];
  const float* gamma = (const float*)d_in[1];
  const float* beta = (const float*)d_in[2];
  const float* wq = (const float*)d_in[3];
  const float* bq = (const float*)d_in[4];
  const float* wk = (const float*)d_in[5];
  const float* bk = (const float*)d_in[6];
  const float* wv = (const float*)d_in[7];
  const float* bv = (const float*)d_in[8];
  const float* wp = (const float*)d_in[9];
  const float* bp = (const float*)d_in[10];

  float* out0 = (float*)d_out;              // (2,256,4096)
  float* attn = (float*)d_out + 2097152;    // (2,4096,4096): S^T then P^T

  char* ws = (char*)d_ws;
  unsigned short* wbf = (unsigned short*)(ws + 0);          // 4 x 256x256 bf16
  unsigned short* hnT = (unsigned short*)(ws + 524288);     // (2,4096,256) bf16
  unsigned short* qT = (unsigned short*)(ws + 4718592);     // (2,4096,256) bf16
  unsigned short* kT = (unsigned short*)(ws + 8912896);     // (2,4096,256) bf16
  unsigned short* vbuf = (unsigned short*)(ws + 13107200);  // (2,256,4096) bf16
  unsigned short* hvT = (unsigned short*)(ws + 17301504);   // (2,4096,256) bf16
  float* gmean = (float*)(ws + 21495808);                   // 64
  float* grstd = (float*)(ws + 21496064);                   // 64
  float* pmax = (float*)(ws + 21496320);                    // 2*8*4096
  float* psum = (float*)(ws + 21758464);                    // 2*8*4096
  float* gmax = (float*)(ws + 22020608);                    // 2*4096
  float* grsum = (float*)(ws + 22053376);                   // 2*4096
  unsigned short* Pbf = (unsigned short*)(ws + 22086144);   // (2,4096,4096) bf16

  const long long NC = 1048576;   // 4096*256 (also 256*4096)
  const long long NN = 16777216;  // 4096*4096

  conv_w_kernel<<<dim3(256, 1, 4), 256, 0, stream>>>(wq, wk, wv, wp, wbf);
  gn_stats_kernel<<<64, 256, 0, stream>>>(x, gmean, grstd);
  gn_apply_t_kernel<<<dim3(64, 4, 2), 256, 0, stream>>>(x, gamma, beta, gmean, grstd, hnT);

  // Q,K: transposed bf16 stores; V: natural bf16 store.
  gemm_tn<64, 128, 3><<<dim3(32, 4, 2), 256, 0, stream>>>(
      (const bf16_t*)wbf, 0, (const bf16_t*)hnT, NC, qT, NC, bq, nullptr, 0, 1.f, 256, 4096, 256);
  gemm_tn<64, 128, 3><<<dim3(32, 4, 2), 256, 0, stream>>>(
      (const bf16_t*)(wbf + 65536), 0, (const bf16_t*)hnT, NC, kT, NC, bk, nullptr, 0, 1.f, 256,
      4096, 256);
  gemm_tn<64, 128, 2><<<dim3(32, 4, 2), 256, 0, stream>>>(
      (const bf16_t*)(wbf + 131072), 0, (const bf16_t*)hnT, NC, vbuf, NC, bv, nullptr, 0, 1.f, 256,
      4096, 256);

  // S^T[m][n] = (k[:,m] . q[:,n]) / 16  -> fp32 into d_out attn region
  gemm_tn<128, 128, 0><<<dim3(32, 32, 2), 256, 0, stream>>>(
      (const bf16_t*)kT, NC, (const bf16_t*)qT, NC, attn, NN, nullptr, nullptr, 0, 0.0625f, 4096,
      4096, 256);

  softmax_part_kernel<<<dim3(16, 8, 2), 256, 0, stream>>>(attn, pmax, psum);
  softmax_comb_kernel<<<dim3(16, 2), 256, 0, stream>>>(pmax, psum, gmax, grsum);
  softmax_norm_t_kernel<<<dim3(64, 64, 2), 256, 0, stream>>>(attn, gmax, grsum, Pbf);

  // hv[c][n] = sum_m v[c][m] P[n][m] -> transposed store hvT[n][c]
  gemm_tn<64, 128, 3><<<dim3(32, 4, 2), 256, 0, stream>>>(
      (const bf16_t*)vbuf, NC, (const bf16_t*)Pbf, NN, hvT, NC, nullptr, nullptr, 0, 1.f, 256, 4096,
      4096);

  // out0 = x + wp . hv + bp
  gemm_tn<64, 128, 1><<<dim3(32, 4, 2), 256, 0, stream>>>(
      (const bf16_t*)(wbf + 196608), 0, (const bf16_t*)hvT, NC, out0, NC, bp, x, NC, 1.f, 256, 4096,
      256);
}

// Round 2
// 355.610 us; speedup vs baseline: 1.4351x; 1.4351x over previous
//
#include <hip/hip_runtime.h>

// AttnBlock: b=2, c=256, n=4096 (16^3), G=32 groups.
// d_out = [ out0: (2,256,4096) fp32 | attn: (2,4096,4096) fp32 (P^T) ]
// Pipeline: GN -> QKV (bf16 MFMA) -> QK^T with fused exp+colsum epilogue ->
//           combine -> scale+transpose (P fp32 out) -> (wp·v)·E^T fused GEMM.
// All GEMMs TN (A=[M][K], B=[N][K], K contiguous), mfma_f32_16x16x32_bf16.

typedef __bf16 bf16_t;
typedef __bf16 bf16x8 __attribute__((ext_vector_type(8)));
typedef float floatx4 __attribute__((ext_vector_type(4)));

__device__ __forceinline__ unsigned short f2bf(float f) {
  union { float f; unsigned int u; } v; v.f = f;
  return (unsigned short)((v.u + 0x7FFFu + ((v.u >> 16) & 1u)) >> 16);
}
__device__ __forceinline__ float bf2f(unsigned short u) {
  union { unsigned int u; float f; } v; v.u = ((unsigned int)u) << 16;
  return v.f;
}

// ---------------- weight fp32 -> bf16 convert (wq,wk,wv,wp) ----------------
__global__ void conv_w_kernel(const float* __restrict__ w0, const float* __restrict__ w1,
                              const float* __restrict__ w2, const float* __restrict__ w3,
                              unsigned short* __restrict__ dst) {
  const float* src = (blockIdx.z == 0) ? w0 : (blockIdx.z == 1) ? w1 : (blockIdx.z == 2) ? w2 : w3;
  int i = blockIdx.x * 256 + threadIdx.x;
  dst[(size_t)blockIdx.z * 65536 + i] = f2bf(src[i]);
}

// ---------------- GroupNorm stats: one block per (b,g) ---------------------
__global__ void gn_stats_kernel(const float* __restrict__ x, float* __restrict__ mean,
                                float* __restrict__ rstd) {
  int bg = blockIdx.x;  // b*32+g
  const float* p = x + (size_t)bg * 32768;
  float s = 0.f, ss = 0.f;
  for (int i = threadIdx.x * 4; i < 32768; i += 1024) {
    float4 v = *(const float4*)&p[i];
    s += v.x + v.y + v.z + v.w;
    ss += v.x * v.x + v.y * v.y + v.z * v.z + v.w * v.w;
  }
  for (int off = 32; off > 0; off >>= 1) {
    s += __shfl_down(s, off);
    ss += __shfl_down(ss, off);
  }
  __shared__ float bs[4], bss[4];
  int wid = threadIdx.x >> 6;
  if ((threadIdx.x & 63) == 0) { bs[wid] = s; bss[wid] = ss; }
  __syncthreads();
  if (threadIdx.x == 0) {
    float S = bs[0] + bs[1] + bs[2] + bs[3];
    float SS = bss[0] + bss[1] + bss[2] + bss[3];
    float mu = S * (1.f / 32768.f);
    float var = SS * (1.f / 32768.f) - mu * mu;
    mean[bg] = mu;
    rstd[bg] = rsqrtf(var + 1e-6f);
  }
}

// ---------------- GroupNorm apply + transpose: write hnT[b][n][c] bf16 -----
__global__ void gn_apply_t_kernel(const float* __restrict__ x, const float* __restrict__ gamma,
                                  const float* __restrict__ beta, const float* __restrict__ mean,
                                  const float* __restrict__ rstd, unsigned short* __restrict__ hnT) {
  int n0 = blockIdx.x * 64, c0 = blockIdx.y * 64, b = blockIdx.z;
  int tid = threadIdx.x;
  __shared__ __align__(16) unsigned short T[64 * 72];
#pragma unroll
  for (int r = 0; r < 4; ++r) {
    int cl = (tid >> 4) + r * 16;
    int nl = (tid & 15) * 4;
    int c = c0 + cl;
    int bg = b * 32 + (c >> 3);
    float mu = mean[bg], rs = rstd[bg], ga = gamma[c], be = beta[c];
    float4 v = *(const float4*)&x[(size_t)b * 1048576 + (size_t)c * 4096 + n0 + nl];
    ushort4 u;
    u.x = f2bf((v.x - mu) * rs * ga + be);
    u.y = f2bf((v.y - mu) * rs * ga + be);
    u.z = f2bf((v.z - mu) * rs * ga + be);
    u.w = f2bf((v.w - mu) * rs * ga + be);
    *(ushort4*)&T[cl * 72 + nl] = u;
  }
  __syncthreads();
#pragma unroll
  for (int w = 0; w < 2; ++w) {
    int nl = (tid >> 3) + w * 32;
    int cch = (tid & 7) * 8;
    unsigned short u8[8];
#pragma unroll
    for (int i = 0; i < 8; ++i) u8[i] = T[(cch + i) * 72 + nl];
    size_t o = (size_t)b * 1048576 + (size_t)(n0 + nl) * 256 + c0 + cch;
    *(ushort4*)&hnT[o] = make_ushort4(u8[0], u8[1], u8[2], u8[3]);
    *(ushort4*)&hnT[o + 4] = make_ushort4(u8[4], u8[5], u8[6], u8[7]);
  }
}

// ---------------- Generic TN bf16 MFMA GEMM --------------------------------
// C[m][n] = scale * sum_k A[m][k]*B[n][k]
// MODE 0: fp32 natural. MODE 1: fp32 natural + bias + resid.
// MODE 2: bf16 natural (+bias). MODE 3: bf16 transposed CT[n*M+m] (+bias).
// MODE 4: fp32 natural, v = acc*colscale[n] + bias[m] + resid[m][n].
template <int BM, int BN, int MODE>
__launch_bounds__(256)
__global__ void gemm_tn(const bf16_t* __restrict__ A0, long long sA,
                        const bf16_t* __restrict__ B0, long long sB,
                        void* __restrict__ C0, long long sC,
                        const float* __restrict__ bias,
                        const float* __restrict__ resid, long long sR,
                        const float* __restrict__ colscale,
                        float scale, int M, int N, int K) {
  constexpr int BK = 32, LD = BK + 8;
  constexpr int WM = BM / 2, WN = BN / 2, MI = WM / 16, NI = WN / 16;
  __shared__ __align__(16) bf16_t As[BM * LD];
  __shared__ __align__(16) bf16_t Bs[BN * LD];
  const int tid = threadIdx.x;
  const int lane = tid & 63, wid = tid >> 6;
  const int quad = lane >> 4, l16 = lane & 15;
  const int bz = blockIdx.z;
  const bf16_t* A = A0 + (size_t)bz * sA;
  const bf16_t* B = B0 + (size_t)bz * sB;
  const int m0 = blockIdx.y * BM, n0 = blockIdx.x * BN;
  const int wm0 = (wid >> 1) * WM, wn0 = (wid & 1) * WN;

  floatx4 acc[MI][NI];
#pragma unroll
  for (int i = 0; i < MI; ++i)
#pragma unroll
    for (int j = 0; j < NI; ++j) acc[i][j] = (floatx4){0.f, 0.f, 0.f, 0.f};

  const int arow = tid >> 2, akj = (tid & 3) << 3;
  for (int kt = 0; kt < K; kt += BK) {
#pragma unroll
    for (int p = 0; p < BM / 64; ++p) {
      int r = p * 64 + arow;
      *(uint4*)&As[r * LD + akj] = *(const uint4*)&A[(size_t)(m0 + r) * K + kt + akj];
    }
#pragma unroll
    for (int p = 0; p < BN / 64; ++p) {
      int r = p * 64 + arow;
      *(uint4*)&Bs[r * LD + akj] = *(const uint4*)&B[(size_t)(n0 + r) * K + kt + akj];
    }
    __syncthreads();
    bf16x8 af[MI], bfr[NI];
#pragma unroll
    for (int i = 0; i < MI; ++i) af[i] = *(const bf16x8*)&As[(wm0 + i * 16 + l16) * LD + quad * 8];
#pragma unroll
    for (int j = 0; j < NI; ++j) bfr[j] = *(const bf16x8*)&Bs[(wn0 + j * 16 + l16) * LD + quad * 8];
#pragma unroll
    for (int i = 0; i < MI; ++i)
#pragma unroll
      for (int j = 0; j < NI; ++j)
        acc[i][j] = __builtin_amdgcn_mfma_f32_16x16x32_bf16(af[i], bfr[j], acc[i][j], 0, 0, 0);
    __syncthreads();
  }

#pragma unroll
  for (int i = 0; i < MI; ++i) {
    int gmb = m0 + wm0 + i * 16 + quad * 4;
#pragma unroll
    for (int j = 0; j < NI; ++j) {
      int gn = n0 + wn0 + j * 16 + l16;
      float v[4];
      if (MODE == 4) {
        float cs = colscale[(size_t)bz * 4096 + gn];
#pragma unroll
        for (int r = 0; r < 4; ++r)
          v[r] = acc[i][j][r] * cs + bias[gmb + r] +
                 resid[(size_t)bz * sR + (size_t)(gmb + r) * N + gn];
        float* Cf = (float*)C0 + (size_t)bz * sC;
#pragma unroll
        for (int r = 0; r < 4; ++r) Cf[(size_t)(gmb + r) * N + gn] = v[r];
        continue;
      }
#pragma unroll
      for (int r = 0; r < 4; ++r) v[r] = acc[i][j][r] * scale;
      if (MODE != 0 && bias != nullptr) {
#pragma unroll
        for (int r = 0; r < 4; ++r) v[r] += bias[gmb + r];
      }
      if (MODE == 0 || MODE == 1) {
        float* Cf = (float*)C0 + (size_t)bz * sC;
        if (MODE == 1 && resid != nullptr) {
#pragma unroll
          for (int r = 0; r < 4; ++r)
            v[r] += resid[(size_t)bz * sR + (size_t)(gmb + r) * N + gn];
        }
#pragma unroll
        for (int r = 0; r < 4; ++r) Cf[(size_t)(gmb + r) * N + gn] = v[r];
      } else if (MODE == 2) {
        unsigned short* Cb = (unsigned short*)C0 + (size_t)bz * sC;
#pragma unroll
        for (int r = 0; r < 4; ++r) Cb[(size_t)(gmb + r) * N + gn] = f2bf(v[r]);
      } else {  // MODE 3
        unsigned short* Cb = (unsigned short*)C0 + (size_t)bz * sC;
        ushort4 u = make_ushort4(f2bf(v[0]), f2bf(v[1]), f2bf(v[2]), f2bf(v[3]));
        *(ushort4*)&Cb[(size_t)gn * M + gmb] = u;
      }
    }
  }
}

// ---------------- QK^T GEMM with fused exp + column-sum partials -----------
// E_bfT[b][n][m] = bf16(exp(S^T[m][n])), psum[b][my][n] = sum over 64-row group.
__launch_bounds__(256)
__global__ void gemm_qk_exp(const bf16_t* __restrict__ kT, const bf16_t* __restrict__ qT,
                            unsigned short* __restrict__ EbfT, float* __restrict__ psum) {
  constexpr int BM = 128, BN = 128, BK = 32, LD = BK + 8, MI = 4, NI = 4;
  __shared__ __align__(16) bf16_t As[BM * LD];
  __shared__ __align__(16) bf16_t Bs[BN * LD];
  const int tid = threadIdx.x;
  const int lane = tid & 63, wid = tid >> 6;
  const int quad = lane >> 4, l16 = lane & 15;
  const int b = blockIdx.z;
  const bf16_t* A = kT + (size_t)b * 1048576;
  const bf16_t* B = qT + (size_t)b * 1048576;
  const int m0 = blockIdx.y * BM, n0 = blockIdx.x * BN;
  const int wm0 = (wid >> 1) * 64, wn0 = (wid & 1) * 64;

  floatx4 acc[MI][NI];
#pragma unroll
  for (int i = 0; i < MI; ++i)
#pragma unroll
    for (int j = 0; j < NI; ++j) acc[i][j] = (floatx4){0.f, 0.f, 0.f, 0.f};

  const int arow = tid >> 2, akj = (tid & 3) << 3;
  for (int kt = 0; kt < 256; kt += BK) {
#pragma unroll
    for (int p = 0; p < 2; ++p) {
      int r = p * 64 + arow;
      *(uint4*)&As[r * LD + akj] = *(const uint4*)&A[(size_t)(m0 + r) * 256 + kt + akj];
      *(uint4*)&Bs[r * LD + akj] = *(const uint4*)&B[(size_t)(n0 + r) * 256 + kt + akj];
    }
    __syncthreads();
    bf16x8 af[MI], bfr[NI];
#pragma unroll
    for (int i = 0; i < MI; ++i) af[i] = *(const bf16x8*)&As[(wm0 + i * 16 + l16) * LD + quad * 8];
#pragma unroll
    for (int j = 0; j < NI; ++j) bfr[j] = *(const bf16x8*)&Bs[(wn0 + j * 16 + l16) * LD + quad * 8];
#pragma unroll
    for (int i = 0; i < MI; ++i)
#pragma unroll
      for (int j = 0; j < NI; ++j)
        acc[i][j] = __builtin_amdgcn_mfma_f32_16x16x32_bf16(af[i], bfr[j], acc[i][j], 0, 0, 0);
    __syncthreads();
  }

  // epilogue: e = exp(s/16); store bf16 transposed [n][m]; per-column sums
  float csum[NI] = {0.f, 0.f, 0.f, 0.f};
#pragma unroll
  for (int i = 0; i < MI; ++i) {
    int gmb = m0 + wm0 + i * 16 + quad * 4;
#pragma unroll
    for (int j = 0; j < NI; ++j) {
      int gn = n0 + wn0 + j * 16 + l16;
      float e[4];
#pragma unroll
      for (int r = 0; r < 4; ++r) e[r] = __expf(acc[i][j][r] * 0.0625f);
      csum[j] += (e[0] + e[1]) + (e[2] + e[3]);
      ushort4 u = make_ushort4(f2bf(e[0]), f2bf(e[1]), f2bf(e[2]), f2bf(e[3]));
      *(ushort4*)&EbfT[(size_t)b * 16777216 + (size_t)gn * 4096 + gmb] = u;
    }
  }
#pragma unroll
  for (int j = 0; j < NI; ++j) {
    csum[j] += __shfl_xor(csum[j], 16);
    csum[j] += __shfl_xor(csum[j], 32);
  }
  if (quad == 0) {
    int my = blockIdx.y * 2 + (wid >> 1);  // 64-row group index
#pragma unroll
    for (int j = 0; j < NI; ++j)
      psum[((size_t)b * 64 + my) * 4096 + n0 + wn0 + j * 16 + l16] = csum[j];
  }
}

// ---------------- combine partial sums -> rsum = 1/colsum ------------------
__global__ void combine_kernel(const float* __restrict__ psum, float* __restrict__ rsum) {
  int b = blockIdx.y;
  int n = blockIdx.x * 256 + threadIdx.x;
  float s = 0.f;
#pragma unroll
  for (int r = 0; r < 64; ++r) s += psum[((size_t)b * 64 + r) * 4096 + n];
  rsum[b * 4096 + n] = 1.f / s;
}

// ---------------- scale + transpose: P[m][n] fp32 = E_bfT[n][m] * rsum[n] --
__global__ void scale_t_kernel(const unsigned short* __restrict__ EbfT,
                               const float* __restrict__ rsum, float* __restrict__ P) {
  constexpr int LDT = 66;
  int m0 = blockIdx.x * 64, n0 = blockIdx.y * 64, b = blockIdx.z;
  int tid = threadIdx.x;
  __shared__ unsigned short T[64 * LDT];
  __shared__ float rs[64];
  if (tid < 64) rs[tid] = rsum[b * 4096 + n0 + tid];
#pragma unroll
  for (int r = 0; r < 2; ++r) {
    int nl = (tid >> 3) + r * 32;
    int ml = (tid & 7) * 8;
    uint4 v = *(const uint4*)&EbfT[(size_t)b * 16777216 + (size_t)(n0 + nl) * 4096 + m0 + ml];
    *(unsigned int*)&T[nl * LDT + ml + 0] = v.x;
    *(unsigned int*)&T[nl * LDT + ml + 2] = v.y;
    *(unsigned int*)&T[nl * LDT + ml + 4] = v.z;
    *(unsigned int*)&T[nl * LDT + ml + 6] = v.w;
  }
  __syncthreads();
#pragma unroll
  for (int rr = 0; rr < 4; ++rr) {
    int ml = (tid >> 4) + rr * 16;
    int nlb = (tid & 15) * 4;
    float4 o;
    o.x = bf2f(T[(nlb + 0) * LDT + ml]) * rs[nlb + 0];
    o.y = bf2f(T[(nlb + 1) * LDT + ml]) * rs[nlb + 1];
    o.z = bf2f(T[(nlb + 2) * LDT + ml]) * rs[nlb + 2];
    o.w = bf2f(T[(nlb + 3) * LDT + ml]) * rs[nlb + 3];
    *(float4*)&P[(size_t)b * 16777216 + (size_t)(m0 + ml) * 4096 + n0 + nlb] = o;
  }
}

extern "C" void kernel_launch(void* const* d_in, const int* in_sizes, int n_in,
                              void* d_out, int out_size, void* d_ws, size_t ws_size,
                              hipStream_t stream) {
  const float* x = (const float*)d_in[0];
  const float* gamma = (const float*)d_in[1];
  const float* beta = (const float*)d_in[2];
  const float* wq = (const float*)d_in[3];
  const float* bq = (const float*)d_in[4];
  const float* wk = (const float*)d_in[5];
  const float* bk = (const float*)d_in[6];
  const float* wv = (const float*)d_in[7];
  const float* bv = (const float*)d_in[8];
  const float* wp = (const float*)d_in[9];
  const float* bp = (const float*)d_in[10];

  float* out0 = (float*)d_out;            // (2,256,4096)
  float* attn = (float*)d_out + 2097152;  // (2,4096,4096) = P^T fp32

  char* ws = (char*)d_ws;
  unsigned short* wbf = (unsigned short*)(ws + 0);        // 4 x 256x256 bf16
  unsigned short* hnT = (unsigned short*)(ws + 524288);   // (2,4096,256) bf16 [dead after V]
  float* psum = (float*)(ws + 524288);                    // (2,64,4096) fp32 [reuses hnT]
  float* rsum = (float*)(ws + 2621440);                   // (2,4096) fp32 [reuses hnT]
  unsigned short* qT = (unsigned short*)(ws + 4718592);   // (2,4096,256) bf16
  unsigned short* kT = (unsigned short*)(ws + 8912896);   // (2,4096,256) bf16
  unsigned short* vT = (unsigned short*)(ws + 13107200);  // (2,4096,256) bf16
  unsigned short* W2 = (unsigned short*)(ws + 17301504);  // (2,256,4096) bf16 = wp·v
  float* gmean = (float*)(ws + 21495808);                 // 64
  float* grstd = (float*)(ws + 21496064);                 // 64
  unsigned short* EbfT = (unsigned short*)(ws + 21496320);  // (2,4096,4096) bf16

  const long long NC = 1048576;   // 4096*256
  const long long NN = 16777216;  // 4096*4096

  conv_w_kernel<<<dim3(256, 1, 4), 256, 0, stream>>>(wq, wk, wv, wp, wbf);
  gn_stats_kernel<<<64, 256, 0, stream>>>(x, gmean, grstd);
  gn_apply_t_kernel<<<dim3(64, 4, 2), 256, 0, stream>>>(x, gamma, beta, gmean, grstd, hnT);

  // q^T, k^T, v^T: all transposed bf16 stores [n][c] / [m][c]
  gemm_tn<64, 128, 3><<<dim3(32, 4, 2), 256, 0, stream>>>(
      (const bf16_t*)wbf, 0, (const bf16_t*)hnT, NC, qT, NC, bq, nullptr, 0, nullptr, 1.f, 256,
      4096, 256);
  gemm_tn<64, 128, 3><<<dim3(32, 4, 2), 256, 0, stream>>>(
      (const bf16_t*)(wbf + 65536), 0, (const bf16_t*)hnT, NC, kT, NC, bk, nullptr, 0, nullptr, 1.f,
      256, 4096, 256);
  gemm_tn<64, 128, 3><<<dim3(32, 4, 2), 256, 0, stream>>>(
      (const bf16_t*)(wbf + 131072), 0, (const bf16_t*)hnT, NC, vT, NC, bv, nullptr, 0, nullptr,
      1.f, 256, 4096, 256);

  // W2[o][m] = sum_c wp[o][c] v[c][m]  (natural bf16 store)
  gemm_tn<64, 128, 2><<<dim3(32, 4, 2), 256, 0, stream>>>(
      (const bf16_t*)(wbf + 196608), 0, (const bf16_t*)vT, NC, W2, NC, nullptr, nullptr, 0, nullptr,
      1.f, 256, 4096, 256);

  // E_bfT[n][m] = exp(S^T[m][n]) bf16 + column partial sums
  gemm_qk_exp<<<dim3(32, 32, 2), 256, 0, stream>>>((const bf16_t*)kT, (const bf16_t*)qT,
                                                   EbfT, psum);
  combine_kernel<<<dim3(16, 2), 256, 0, stream>>>(psum, rsum);

  // P^T fp32 into d_out
  scale_t_kernel<<<dim3(64, 64, 2), 256, 0, stream>>>(EbfT, rsum, attn);

  // out0[o][n] = rsum[n] * sum_m W2[o][m] E_bfT[n][m] + bp[o] + x[o][n]
  gemm_tn<128, 64, 4><<<dim3(64, 2, 2), 256, 0, stream>>>(
      (const bf16_t*)W2, NC, (const bf16_t*)EbfT, NN, out0, NC, bp, x, NC, rsum, 1.f, 256, 4096,
      4096);
}

// Round 3
// 314.575 us; speedup vs baseline: 1.6223x; 1.1304x over previous
//
#include <hip/hip_runtime.h>

// AttnBlock: b=2, c=256, n=4096 (16^3), G=32 groups.
// d_out = [ out0: (2,256,4096) fp32 | attn: (2,4096,4096) fp32 (P^T) ]
// Pipeline: GN -> merged QKV GEMM (M=768) -> W2=wp·v -> QK^T w/ fused exp+colsum
//           (coalesced E^T bf16 via LDS transpose) -> combine -> fused PV GEMM
//           (stages E^T, writes P^T fp32 in-pass, K-split 2) -> reduce(+bias+x).

typedef __bf16 bf16_t;
typedef __bf16 bf16x8 __attribute__((ext_vector_type(8)));
typedef float floatx4 __attribute__((ext_vector_type(4)));

__device__ __forceinline__ unsigned short f2bf(float f) {
  union { float f; unsigned int u; } v; v.f = f;
  return (unsigned short)((v.u + 0x7FFFu + ((v.u >> 16) & 1u)) >> 16);
}
__device__ __forceinline__ float bf2f(unsigned short u) {
  union { unsigned int u; float f; } v; v.u = ((unsigned int)u) << 16;
  return v.f;
}

// ---------------- weight fp32 -> bf16 (wq,wk,wv,wp) ------------------------
__global__ void conv_w_kernel(const float* __restrict__ w0, const float* __restrict__ w1,
                              const float* __restrict__ w2, const float* __restrict__ w3,
                              unsigned short* __restrict__ dst) {
  const float* src = (blockIdx.z == 0) ? w0 : (blockIdx.z == 1) ? w1 : (blockIdx.z == 2) ? w2 : w3;
  int i = blockIdx.x * 256 + threadIdx.x;
  dst[(size_t)blockIdx.z * 65536 + i] = f2bf(src[i]);
}

// ---------------- pack bq,bk,bv -> bqkv[768] -------------------------------
__global__ void pack_bias_kernel(const float* __restrict__ bq, const float* __restrict__ bk,
                                 const float* __restrict__ bv, float* __restrict__ bqkv) {
  int t = threadIdx.x;
  bqkv[t] = bq[t];
  bqkv[256 + t] = bk[t];
  bqkv[512 + t] = bv[t];
}

// ---------------- GroupNorm stats ------------------------------------------
__global__ void gn_stats_kernel(const float* __restrict__ x, float* __restrict__ mean,
                                float* __restrict__ rstd) {
  int bg = blockIdx.x;
  const float* p = x + (size_t)bg * 32768;
  float s = 0.f, ss = 0.f;
  for (int i = threadIdx.x * 4; i < 32768; i += 1024) {
    float4 v = *(const float4*)&p[i];
    s += v.x + v.y + v.z + v.w;
    ss += v.x * v.x + v.y * v.y + v.z * v.z + v.w * v.w;
  }
  for (int off = 32; off > 0; off >>= 1) {
    s += __shfl_down(s, off);
    ss += __shfl_down(ss, off);
  }
  __shared__ float bs[4], bss[4];
  int wid = threadIdx.x >> 6;
  if ((threadIdx.x & 63) == 0) { bs[wid] = s; bss[wid] = ss; }
  __syncthreads();
  if (threadIdx.x == 0) {
    float S = bs[0] + bs[1] + bs[2] + bs[3];
    float SS = bss[0] + bss[1] + bss[2] + bss[3];
    float mu = S * (1.f / 32768.f);
    float var = SS * (1.f / 32768.f) - mu * mu;
    mean[bg] = mu;
    rstd[bg] = rsqrtf(var + 1e-6f);
  }
}

// ---------------- GroupNorm apply + transpose -> hnT[b][n][c] bf16 ---------
__global__ void gn_apply_t_kernel(const float* __restrict__ x, const float* __restrict__ gamma,
                                  const float* __restrict__ beta, const float* __restrict__ mean,
                                  const float* __restrict__ rstd, unsigned short* __restrict__ hnT) {
  int n0 = blockIdx.x * 64, c0 = blockIdx.y * 64, b = blockIdx.z;
  int tid = threadIdx.x;
  __shared__ __align__(16) unsigned short T[64 * 72];
#pragma unroll
  for (int r = 0; r < 4; ++r) {
    int cl = (tid >> 4) + r * 16;
    int nl = (tid & 15) * 4;
    int c = c0 + cl;
    int bg = b * 32 + (c >> 3);
    float mu = mean[bg], rs = rstd[bg], ga = gamma[c], be = beta[c];
    float4 v = *(const float4*)&x[(size_t)b * 1048576 + (size_t)c * 4096 + n0 + nl];
    ushort4 u;
    u.x = f2bf((v.x - mu) * rs * ga + be);
    u.y = f2bf((v.y - mu) * rs * ga + be);
    u.z = f2bf((v.z - mu) * rs * ga + be);
    u.w = f2bf((v.w - mu) * rs * ga + be);
    *(ushort4*)&T[cl * 72 + nl] = u;
  }
  __syncthreads();
#pragma unroll
  for (int w = 0; w < 2; ++w) {
    int nl = (tid >> 3) + w * 32;
    int cch = (tid & 7) * 8;
    unsigned short u8[8];
#pragma unroll
    for (int i = 0; i < 8; ++i) u8[i] = T[(cch + i) * 72 + nl];
    size_t o = (size_t)b * 1048576 + (size_t)(n0 + nl) * 256 + c0 + cch;
    *(ushort4*)&hnT[o] = make_ushort4(u8[0], u8[1], u8[2], u8[3]);
    *(ushort4*)&hnT[o + 4] = make_ushort4(u8[4], u8[5], u8[6], u8[7]);
  }
}

// ---------------- Generic TN bf16 MFMA GEMM --------------------------------
// C[m][n] = sum_k A[m][k]*B[n][k] (+bias[m])
// MODE 2: bf16 natural store. MODE 3: bf16 transposed store CT[n*M+m].
template <int BM, int BN, int MODE>
__launch_bounds__(256)
__global__ void gemm_tn(const bf16_t* __restrict__ A0, long long sA,
                        const bf16_t* __restrict__ B0, long long sB, int ldb,
                        void* __restrict__ C0, long long sC,
                        const float* __restrict__ bias, int M, int N, int K) {
  constexpr int BK = 32, LD = BK + 8;
  constexpr int WM = BM / 2, WN = BN / 2, MI = WM / 16, NI = WN / 16;
  __shared__ __align__(16) bf16_t As[BM * LD];
  __shared__ __align__(16) bf16_t Bs[BN * LD];
  const int tid = threadIdx.x;
  const int lane = tid & 63, wid = tid >> 6;
  const int quad = lane >> 4, l16 = lane & 15;
  const int bz = blockIdx.z;
  const bf16_t* A = A0 + (size_t)bz * sA;
  const bf16_t* B = B0 + (size_t)bz * sB;
  const int m0 = blockIdx.y * BM, n0 = blockIdx.x * BN;
  const int wm0 = (wid >> 1) * WM, wn0 = (wid & 1) * WN;

  floatx4 acc[MI][NI];
#pragma unroll
  for (int i = 0; i < MI; ++i)
#pragma unroll
    for (int j = 0; j < NI; ++j) acc[i][j] = (floatx4){0.f, 0.f, 0.f, 0.f};

  const int arow = tid >> 2, akj = (tid & 3) << 3;
  for (int kt = 0; kt < K; kt += BK) {
#pragma unroll
    for (int p = 0; p < BM / 64; ++p) {
      int r = p * 64 + arow;
      *(uint4*)&As[r * LD + akj] = *(const uint4*)&A[(size_t)(m0 + r) * K + kt + akj];
    }
#pragma unroll
    for (int p = 0; p < BN / 64; ++p) {
      int r = p * 64 + arow;
      *(uint4*)&Bs[r * LD + akj] = *(const uint4*)&B[(size_t)(n0 + r) * ldb + kt + akj];
    }
    __syncthreads();
    bf16x8 af[MI], bfr[NI];
#pragma unroll
    for (int i = 0; i < MI; ++i) af[i] = *(const bf16x8*)&As[(wm0 + i * 16 + l16) * LD + quad * 8];
#pragma unroll
    for (int j = 0; j < NI; ++j) bfr[j] = *(const bf16x8*)&Bs[(wn0 + j * 16 + l16) * LD + quad * 8];
#pragma unroll
    for (int i = 0; i < MI; ++i)
#pragma unroll
      for (int j = 0; j < NI; ++j)
        acc[i][j] = __builtin_amdgcn_mfma_f32_16x16x32_bf16(af[i], bfr[j], acc[i][j], 0, 0, 0);
    __syncthreads();
  }

#pragma unroll
  for (int i = 0; i < MI; ++i) {
    int gmb = m0 + wm0 + i * 16 + quad * 4;
#pragma unroll
    for (int j = 0; j < NI; ++j) {
      int gn = n0 + wn0 + j * 16 + l16;
      float v[4];
#pragma unroll
      for (int r = 0; r < 4; ++r) v[r] = acc[i][j][r];
      if (bias != nullptr) {
#pragma unroll
        for (int r = 0; r < 4; ++r) v[r] += bias[gmb + r];
      }
      if (MODE == 2) {
        unsigned short* Cb = (unsigned short*)C0 + (size_t)bz * sC;
#pragma unroll
        for (int r = 0; r < 4; ++r) Cb[(size_t)(gmb + r) * N + gn] = f2bf(v[r]);
      } else {  // MODE 3
        unsigned short* Cb = (unsigned short*)C0 + (size_t)bz * sC;
        ushort4 u = make_ushort4(f2bf(v[0]), f2bf(v[1]), f2bf(v[2]), f2bf(v[3]));
        *(ushort4*)&Cb[(size_t)gn * M + gmb] = u;
      }
    }
  }
}

// ---------------- QK^T + exp + colsum, coalesced E^T store -----------------
// E_bfT[b][n][m] = bf16(exp(qK/16)), psum[b][my][n] partial col-sums.
__launch_bounds__(256)
__global__ void gemm_qk_exp(const bf16_t* __restrict__ qkvT, unsigned short* __restrict__ EbfT,
                            float* __restrict__ psum) {
  constexpr int BM = 128, BN = 128, BK = 32, LD = BK + 8, MI = 4, NI = 4;
  constexpr int LDC = BM + 8;  // 136
  __shared__ __align__(16) char SMEM[BM * LDC * 2];  // 34816 B; aliases As+Bs (20480 B)
  bf16_t* As = (bf16_t*)SMEM;
  bf16_t* Bs = (bf16_t*)SMEM + BM * LD;
  unsigned short* Ct = (unsigned short*)SMEM;  // [BN][LDC], m-contiguous
  const int tid = threadIdx.x;
  const int lane = tid & 63, wid = tid >> 6;
  const int quad = lane >> 4, l16 = lane & 15;
  const int b = blockIdx.z;
  const bf16_t* A = qkvT + (size_t)b * 3145728 + 256;  // k
  const bf16_t* B = qkvT + (size_t)b * 3145728;        // q
  const int m0 = blockIdx.y * BM, n0 = blockIdx.x * BN;
  const int wm0 = (wid >> 1) * 64, wn0 = (wid & 1) * 64;

  floatx4 acc[MI][NI];
#pragma unroll
  for (int i = 0; i < MI; ++i)
#pragma unroll
    for (int j = 0; j < NI; ++j) acc[i][j] = (floatx4){0.f, 0.f, 0.f, 0.f};

  const int arow = tid >> 2, akj = (tid & 3) << 3;
  for (int kt = 0; kt < 256; kt += BK) {
#pragma unroll
    for (int p = 0; p < 2; ++p) {
      int r = p * 64 + arow;
      *(uint4*)&As[r * LD + akj] = *(const uint4*)&A[(size_t)(m0 + r) * 768 + kt + akj];
      *(uint4*)&Bs[r * LD + akj] = *(const uint4*)&B[(size_t)(n0 + r) * 768 + kt + akj];
    }
    __syncthreads();
    bf16x8 af[MI], bfr[NI];
#pragma unroll
    for (int i = 0; i < MI; ++i) af[i] = *(const bf16x8*)&As[(wm0 + i * 16 + l16) * LD + quad * 8];
#pragma unroll
    for (int j = 0; j < NI; ++j) bfr[j] = *(const bf16x8*)&Bs[(wn0 + j * 16 + l16) * LD + quad * 8];
#pragma unroll
    for (int i = 0; i < MI; ++i)
#pragma unroll
      for (int j = 0; j < NI; ++j)
        acc[i][j] = __builtin_amdgcn_mfma_f32_16x16x32_bf16(af[i], bfr[j], acc[i][j], 0, 0, 0);
    __syncthreads();
  }

  // exp + colsum + scatter bf16 into LDS Ct[n_local][m_local]
  float csum[NI] = {0.f, 0.f, 0.f, 0.f};
#pragma unroll
  for (int i = 0; i < MI; ++i) {
    int ml = wm0 + i * 16 + quad * 4;
#pragma unroll
    for (int j = 0; j < NI; ++j) {
      int nl = wn0 + j * 16 + l16;
      float e[4];
#pragma unroll
      for (int r = 0; r < 4; ++r) e[r] = __expf(acc[i][j][r] * 0.0625f);
      csum[j] += (e[0] + e[1]) + (e[2] + e[3]);
      *(ushort4*)&Ct[nl * LDC + ml] = make_ushort4(f2bf(e[0]), f2bf(e[1]), f2bf(e[2]), f2bf(e[3]));
    }
  }
#pragma unroll
  for (int j = 0; j < NI; ++j) {
    csum[j] += __shfl_xor(csum[j], 16);
    csum[j] += __shfl_xor(csum[j], 32);
  }
  if (quad == 0) {
    int my = blockIdx.y * 2 + (wid >> 1);
#pragma unroll
    for (int j = 0; j < NI; ++j)
      psum[((size_t)b * 64 + my) * 4096 + n0 + wn0 + j * 16 + l16] = csum[j];
  }
  __syncthreads();
  // coalesced 16B stores of E^T rows
#pragma unroll
  for (int pass = 0; pass < 8; ++pass) {
    int row = pass * 16 + (tid >> 4);
    int mc = (tid & 15) * 8;
    uint4 v = *(uint4*)&Ct[row * LDC + mc];
    *(uint4*)&EbfT[(size_t)b * 16777216 + (size_t)(n0 + row) * 4096 + m0 + mc] = v;
  }
}

// ---------------- combine partial sums -> rsum = 1/colsum ------------------
__global__ void combine_kernel(const float* __restrict__ psum, float* __restrict__ rsum) {
  int b = blockIdx.y;
  int n = blockIdx.x * 256 + threadIdx.x;
  float s = 0.f;
#pragma unroll
  for (int r = 0; r < 64; ++r) s += psum[((size_t)b * 64 + r) * 4096 + n];
  rsum[b * 4096 + n] = 1.f / s;
}

// ---------------- fused PV GEMM + P^T write, K-split 2 ---------------------
// part[kb][b][o][n] = rsum[n] * sum_{m in half} W2[o][m] E^T[m][n]
// and attn[b][m][n] = bf2f(E^T[n][m]) * rsum[n]  (P^T fp32, written in-pass)
__launch_bounds__(512)
__global__ void gemm_pv_fused(const bf16_t* __restrict__ W2, const bf16_t* __restrict__ EbfT,
                              const float* __restrict__ rsum, float* __restrict__ attn,
                              float* __restrict__ part0, float* __restrict__ part1) {
  constexpr int BK = 32, LD = BK + 8;
  __shared__ __align__(16) bf16_t As[256 * LD];
  __shared__ __align__(16) bf16_t Bs[64 * LD];
  __shared__ float rs[64];
  const int tid = threadIdx.x;
  const int lane = tid & 63, wid = tid >> 6;
  const int quad = lane >> 4, l16 = lane & 15;
  const int kb = blockIdx.y, b = blockIdx.z;
  const int n0 = blockIdx.x * 64;
  const size_t eb = (size_t)b * 16777216;
  if (tid < 64) rs[tid] = rsum[b * 4096 + n0 + tid];
  __syncthreads();
  const int wm0 = (wid >> 1) * 64, wn0 = (wid & 1) * 32;

  floatx4 acc[4][2];
#pragma unroll
  for (int i = 0; i < 4; ++i)
#pragma unroll
    for (int j = 0; j < 2; ++j) acc[i][j] = (floatx4){0.f, 0.f, 0.f, 0.f};

  const int ar = tid >> 2, ak = (tid & 3) << 3;
  for (int kt = 0; kt < 2048; kt += BK) {
    const int gm = kb * 2048 + kt;
#pragma unroll
    for (int p = 0; p < 2; ++p) {
      int r = p * 128 + ar;
      *(uint4*)&As[r * LD + ak] =
          *(const uint4*)&W2[(size_t)b * 1048576 + (size_t)r * 4096 + gm + ak];
    }
    if (tid < 256) {
      int r = tid >> 2;
      int kk = (tid & 3) << 3;
      *(uint4*)&Bs[r * LD + kk] = *(const uint4*)&EbfT[eb + (size_t)(n0 + r) * 4096 + gm + kk];
    }
    __syncthreads();
    // P^T write from staged tile: 32 m-rows x 64 n
    {
      int ml = tid >> 4;
      int n4 = (tid & 15) * 4;
      const unsigned short* Bu = (const unsigned short*)Bs;
      float4 o;
      o.x = bf2f(Bu[(n4 + 0) * LD + ml]) * rs[n4 + 0];
      o.y = bf2f(Bu[(n4 + 1) * LD + ml]) * rs[n4 + 1];
      o.z = bf2f(Bu[(n4 + 2) * LD + ml]) * rs[n4 + 2];
      o.w = bf2f(Bu[(n4 + 3) * LD + ml]) * rs[n4 + 3];
      *(float4*)&attn[eb + (size_t)(gm + ml) * 4096 + n0 + n4] = o;
    }
    bf16x8 af[4], bfr[2];
#pragma unroll
    for (int i = 0; i < 4; ++i) af[i] = *(const bf16x8*)&As[(wm0 + i * 16 + l16) * LD + quad * 8];
#pragma unroll
    for (int j = 0; j < 2; ++j) bfr[j] = *(const bf16x8*)&Bs[(wn0 + j * 16 + l16) * LD + quad * 8];
#pragma unroll
    for (int i = 0; i < 4; ++i)
#pragma unroll
      for (int j = 0; j < 2; ++j)
        acc[i][j] = __builtin_amdgcn_mfma_f32_16x16x32_bf16(af[i], bfr[j], acc[i][j], 0, 0, 0);
    __syncthreads();
  }

  float* part = kb ? part1 : part0;
#pragma unroll
  for (int i = 0; i < 4; ++i) {
    int row = wm0 + i * 16 + quad * 4;
#pragma unroll
    for (int j = 0; j < 2; ++j) {
      int cl = wn0 + j * 16 + l16;
      float cs = rs[cl];
#pragma unroll
      for (int r = 0; r < 4; ++r)
        part[(size_t)b * 1048576 + (size_t)(row + r) * 4096 + n0 + cl] = acc[i][j][r] * cs;
    }
  }
}

// ---------------- reduce: out0 = part0 + part1 + bias + x ------------------
__global__ void reduce_kernel(float* __restrict__ out0, const float* __restrict__ part1,
                              const float* __restrict__ bp, const float* __restrict__ x) {
  size_t idx = ((size_t)blockIdx.x * 256 + threadIdx.x) * 4;
  int o = (int)((idx >> 12) & 255);
  float4 a = *(float4*)&out0[idx];
  float4 p = *(const float4*)&part1[idx];
  float4 xr = *(const float4*)&x[idx];
  float bb = bp[o];
  a.x += p.x + xr.x + bb;
  a.y += p.y + xr.y + bb;
  a.z += p.z + xr.z + bb;
  a.w += p.w + xr.w + bb;
  *(float4*)&out0[idx] = a;
}

extern "C" void kernel_launch(void* const* d_in, const int* in_sizes, int n_in,
                              void* d_out, int out_size, void* d_ws, size_t ws_size,
                              hipStream_t stream) {
  const float* x = (const float*)d_in[0];
  const float* gamma = (const float*)d_in[1];
  const float* beta = (const float*)d_in[2];
  const float* wq = (const float*)d_in[3];
  const float* bq = (const float*)d_in[4];
  const float* wk = (const float*)d_in[5];
  const float* bk = (const float*)d_in[6];
  const float* wv = (const float*)d_in[7];
  const float* bv = (const float*)d_in[8];
  const float* wp = (const float*)d_in[9];
  const float* bp = (const float*)d_in[10];

  float* out0 = (float*)d_out;            // (2,256,4096); also part0 scratch
  float* attn = (float*)d_out + 2097152;  // (2,4096,4096) = P^T fp32

  char* ws = (char*)d_ws;
  unsigned short* wbf = (unsigned short*)(ws + 0);         // 4 x 65536 bf16
  float* bqkv = (float*)(ws + 524288);                     // 768
  float* gmean = (float*)(ws + 528384);                    // 64
  float* grstd = (float*)(ws + 528640);                    // 64
  float* psum = (float*)(ws + 1048576);                    // (2,64,4096)
  float* rsum = (float*)(ws + 3145728);                    // (2,4096)
  unsigned short* hnT = (unsigned short*)(ws + 4194304);   // (2,4096,256) [dead after QKV]
  unsigned short* W2 = (unsigned short*)(ws + 4194304);    // (2,256,4096) [reuses hnT]
  unsigned short* qkvT = (unsigned short*)(ws + 8388608);  // (2,4096,768) [dead after qk_exp]
  float* part1 = (float*)(ws + 8388608);                   // (2,256,4096) [reuses qkvT]
  unsigned short* EbfT = (unsigned short*)(ws + 20971520); // (2,4096,4096) bf16

  conv_w_kernel<<<dim3(256, 1, 4), 256, 0, stream>>>(wq, wk, wv, wp, wbf);
  pack_bias_kernel<<<1, 256, 0, stream>>>(bq, bk, bv, bqkv);
  gn_stats_kernel<<<64, 256, 0, stream>>>(x, gmean, grstd);
  gn_apply_t_kernel<<<dim3(64, 4, 2), 256, 0, stream>>>(x, gamma, beta, gmean, grstd, hnT);

  // merged QKV: qkvT[b][n][768] = {q,k,v} transposed
  gemm_tn<64, 128, 3><<<dim3(32, 12, 2), 256, 0, stream>>>(
      (const bf16_t*)wbf, 0, (const bf16_t*)hnT, 1048576, 256, qkvT, 3145728, bqkv, 768, 4096, 256);

  // W2[b][o][m] = sum_c wp[o][c] v[c][m]; B = vT at qkvT col 512, ldb=768
  gemm_tn<64, 128, 2><<<dim3(32, 4, 2), 256, 0, stream>>>(
      (const bf16_t*)(wbf + 196608), 0, (const bf16_t*)qkvT + 512, 3145728, 768, W2, 1048576,
      nullptr, 256, 4096, 256);

  gemm_qk_exp<<<dim3(32, 32, 2), 256, 0, stream>>>((const bf16_t*)qkvT, EbfT, psum);
  combine_kernel<<<dim3(16, 2), 256, 0, stream>>>(psum, rsum);

  gemm_pv_fused<<<dim3(64, 2, 2), 512, 0, stream>>>((const bf16_t*)W2, (const bf16_t*)EbfT, rsum,
                                                    attn, out0, part1);
  reduce_kernel<<<2048, 256, 0, stream>>>(out0, part1, bp, x);
}

// Round 4
// 277.847 us; speedup vs baseline: 1.8368x; 1.1322x over previous
//
#include <hip/hip_runtime.h>

// AttnBlock: b=2, c=256, n=4096 (16^3), G=32 groups.
// d_out = [ out0: (2,256,4096) fp32 | attn: (2,4096,4096) fp32 (P^T) ]
// Pipeline (6 kernels):
//   1. prep: conv weights->bf16 (wq,wk nat; wv transposed; wp), GN stats,
//      bias packs (bqkv2=[bq,bk,0], bias2=bp+wp·bv)
//   2. wpv GEMM: wpv = wp·wv (bf16) into Astack rows 512-767
//   3. gn_apply -> hnT[b][n][c] bf16
//   4. merged GEMM M=768: rows 0-511 -> qkT[b][n][512] (transposed store),
//      rows 512-767 -> W2[b][o][m] natural (W2 = (wp·wv)·hn)
//   5. qk_exp: E^T bf16 + column psums (no max-sub; |S|<~10 safe in fp32)
//   6. pv_fused: rsum prologue, stages E^T, writes P^T fp32 (d_out) in-pass,
//      MFMA vs W2, direct out0 = acc*rsum + bias2 + x. M-split, 2 blocks/CU.

typedef __bf16 bf16_t;
typedef __bf16 bf16x8 __attribute__((ext_vector_type(8)));
typedef float floatx4 __attribute__((ext_vector_type(4)));

__device__ __forceinline__ unsigned short f2bf(float f) {
  union { float f; unsigned int u; } v; v.f = f;
  return (unsigned short)((v.u + 0x7FFFu + ((v.u >> 16) & 1u)) >> 16);
}
__device__ __forceinline__ float bf2f(unsigned short u) {
  union { unsigned int u; float f; } v; v.u = ((unsigned int)u) << 16;
  return v.f;
}

// ---------------- prep: weight converts + GN stats + bias packs ------------
// blocks 0-255: wq->Astack[0:256]; 256-511: wk->Astack[256:512]; 512-767: wp->wpbf
// 768-783: wv -> wvT bf16 (64x64 LDS transpose tiles)
// 784-847: gn_stats; 848: bqkv2 pack; 849-852: bias2 = bp + wp·bv
__global__ void prep_kernel(const float* __restrict__ wq, const float* __restrict__ wk,
                            const float* __restrict__ wv, const float* __restrict__ wp,
                            const float* __restrict__ bq, const float* __restrict__ bk,
                            const float* __restrict__ bv, const float* __restrict__ bp,
                            const float* __restrict__ x, unsigned short* __restrict__ Astack,
                            unsigned short* __restrict__ wpbf, unsigned short* __restrict__ wvT,
                            float* __restrict__ bqkv2, float* __restrict__ bias2,
                            float* __restrict__ mean, float* __restrict__ rstd) {
  __shared__ float T[64 * 67];
  __shared__ float red[256];
  const int blk = blockIdx.x;
  const int tid = threadIdx.x;
  if (blk < 768) {
    int w = blk >> 8;
    const float* src = (w == 0) ? wq : (w == 1) ? wk : wp;
    unsigned short* dst = (w == 0) ? Astack : (w == 1) ? (Astack + 65536) : wpbf;
    int i = (blk & 255) * 256 + tid;
    dst[i] = f2bf(src[i]);
  } else if (blk < 784) {
    int t = blk - 768, tr = t >> 2, tc = t & 3;
#pragma unroll
    for (int rr = 0; rr < 16; ++rr) {
      int r = rr * 4 + (tid >> 6), c = tid & 63;
      T[r * 67 + c] = wv[(size_t)(tr * 64 + r) * 256 + tc * 64 + c];
    }
    __syncthreads();
#pragma unroll
    for (int rr = 0; rr < 16; ++rr) {
      int cc = rr * 4 + (tid >> 6), r = tid & 63;
      wvT[(size_t)(tc * 64 + cc) * 256 + tr * 64 + r] = f2bf(T[r * 67 + cc]);
    }
  } else if (blk < 848) {
    int bg = blk - 784;
    const float* p = x + (size_t)bg * 32768;
    float s = 0.f, ss = 0.f;
    for (int i = tid * 4; i < 32768; i += 1024) {
      float4 v = *(const float4*)&p[i];
      s += v.x + v.y + v.z + v.w;
      ss += v.x * v.x + v.y * v.y + v.z * v.z + v.w * v.w;
    }
    for (int off = 32; off > 0; off >>= 1) {
      s += __shfl_down(s, off);
      ss += __shfl_down(ss, off);
    }
    int wid = tid >> 6;
    if ((tid & 63) == 0) { red[wid] = s; red[64 + wid] = ss; }
    __syncthreads();
    if (tid == 0) {
      float S = red[0] + red[1] + red[2] + red[3];
      float SS = red[64] + red[65] + red[66] + red[67];
      float mu = S * (1.f / 32768.f);
      float var = SS * (1.f / 32768.f) - mu * mu;
      mean[bg] = mu;
      rstd[bg] = rsqrtf(var + 1e-6f);
    }
  } else if (blk == 848) {
    bqkv2[tid] = bq[tid];
    bqkv2[256 + tid] = bk[tid];
    bqkv2[512 + tid] = 0.f;
  } else {
    int bb = blk - 849;  // 0..3
    int o = bb * 64 + (tid >> 2), part = tid & 3;
    float s = 0.f;
#pragma unroll
    for (int j = 0; j < 16; ++j) {
      float4 w4 = *(const float4*)&wp[(size_t)o * 256 + part * 64 + j * 4];
      float4 b4 = *(const float4*)&bv[part * 64 + j * 4];
      s += w4.x * b4.x + w4.y * b4.y + w4.z * b4.z + w4.w * b4.w;
    }
    red[tid] = s;
    __syncthreads();
    if (part == 0) bias2[o] = bp[o] + red[tid] + red[tid + 1] + red[tid + 2] + red[tid + 3];
  }
}

// ---------------- GroupNorm apply + transpose -> hnT[b][n][c] bf16 ---------
__global__ void gn_apply_t_kernel(const float* __restrict__ x, const float* __restrict__ gamma,
                                  const float* __restrict__ beta, const float* __restrict__ mean,
                                  const float* __restrict__ rstd, unsigned short* __restrict__ hnT) {
  int n0 = blockIdx.x * 64, c0 = blockIdx.y * 64, b = blockIdx.z;
  int tid = threadIdx.x;
  __shared__ __align__(16) unsigned short T[64 * 72];
#pragma unroll
  for (int r = 0; r < 4; ++r) {
    int cl = (tid >> 4) + r * 16;
    int nl = (tid & 15) * 4;
    int c = c0 + cl;
    int bg = b * 32 + (c >> 3);
    float mu = mean[bg], rs = rstd[bg], ga = gamma[c], be = beta[c];
    float4 v = *(const float4*)&x[(size_t)b * 1048576 + (size_t)c * 4096 + n0 + nl];
    ushort4 u;
    u.x = f2bf((v.x - mu) * rs * ga + be);
    u.y = f2bf((v.y - mu) * rs * ga + be);
    u.z = f2bf((v.z - mu) * rs * ga + be);
    u.w = f2bf((v.w - mu) * rs * ga + be);
    *(ushort4*)&T[cl * 72 + nl] = u;
  }
  __syncthreads();
#pragma unroll
  for (int w = 0; w < 2; ++w) {
    int nl = (tid >> 3) + w * 32;
    int cch = (tid & 7) * 8;
    unsigned short u8[8];
#pragma unroll
    for (int i = 0; i < 8; ++i) u8[i] = T[(cch + i) * 72 + nl];
    size_t o = (size_t)b * 1048576 + (size_t)(n0 + nl) * 256 + c0 + cch;
    *(ushort4*)&hnT[o] = make_ushort4(u8[0], u8[1], u8[2], u8[3]);
    *(ushort4*)&hnT[o + 4] = make_ushort4(u8[4], u8[5], u8[6], u8[7]);
  }
}

// ---------------- Generic TN bf16 MFMA GEMM (bf16 natural store) -----------
// C[m][n] = sum_k A[m][k]*B[n][k]
template <int BM, int BN>
__launch_bounds__(256)
__global__ void gemm_tn(const bf16_t* __restrict__ A, const bf16_t* __restrict__ B, int ldb,
                        unsigned short* __restrict__ C, int N, int K) {
  constexpr int BK = 32, LD = BK + 8;
  constexpr int WM = BM / 2, WN = BN / 2, MI = WM / 16, NI = WN / 16;
  __shared__ __align__(16) bf16_t As[BM * LD];
  __shared__ __align__(16) bf16_t Bs[BN * LD];
  const int tid = threadIdx.x;
  const int lane = tid & 63, wid = tid >> 6;
  const int quad = lane >> 4, l16 = lane & 15;
  const int m0 = blockIdx.y * BM, n0 = blockIdx.x * BN;
  const int wm0 = (wid >> 1) * WM, wn0 = (wid & 1) * WN;

  floatx4 acc[MI][NI];
#pragma unroll
  for (int i = 0; i < MI; ++i)
#pragma unroll
    for (int j = 0; j < NI; ++j) acc[i][j] = (floatx4){0.f, 0.f, 0.f, 0.f};

  const int arow = tid >> 2, akj = (tid & 3) << 3;
  for (int kt = 0; kt < K; kt += BK) {
#pragma unroll
    for (int p = 0; p < BM / 64; ++p) {
      int r = p * 64 + arow;
      *(uint4*)&As[r * LD + akj] = *(const uint4*)&A[(size_t)(m0 + r) * K + kt + akj];
    }
#pragma unroll
    for (int p = 0; p < BN / 64; ++p) {
      int r = p * 64 + arow;
      *(uint4*)&Bs[r * LD + akj] = *(const uint4*)&B[(size_t)(n0 + r) * ldb + kt + akj];
    }
    __syncthreads();
    bf16x8 af[MI], bfr[NI];
#pragma unroll
    for (int i = 0; i < MI; ++i) af[i] = *(const bf16x8*)&As[(wm0 + i * 16 + l16) * LD + quad * 8];
#pragma unroll
    for (int j = 0; j < NI; ++j) bfr[j] = *(const bf16x8*)&Bs[(wn0 + j * 16 + l16) * LD + quad * 8];
#pragma unroll
    for (int i = 0; i < MI; ++i)
#pragma unroll
      for (int j = 0; j < NI; ++j)
        acc[i][j] = __builtin_amdgcn_mfma_f32_16x16x32_bf16(af[i], bfr[j], acc[i][j], 0, 0, 0);
    __syncthreads();
  }

#pragma unroll
  for (int i = 0; i < MI; ++i) {
    int gmb = m0 + wm0 + i * 16 + quad * 4;
#pragma unroll
    for (int j = 0; j < NI; ++j) {
      int gn = n0 + wn0 + j * 16 + l16;
#pragma unroll
      for (int r = 0; r < 4; ++r) C[(size_t)(gmb + r) * N + gn] = f2bf(acc[i][j][r]);
    }
  }
}

// ---------------- merged QKV+W2 GEMM (M=768, K=256) ------------------------
// rows 0-511: transposed store -> qkT[b][n][512] (+bias)
// rows 512-767: natural store -> W2[b][o][4096]
__launch_bounds__(256)
__global__ void gemm_qkvw(const bf16_t* __restrict__ Astack, const bf16_t* __restrict__ hnT,
                          const float* __restrict__ bqkv2, unsigned short* __restrict__ qkT,
                          unsigned short* __restrict__ W2) {
  constexpr int BM = 64, BN = 128, BK = 32, LD = BK + 8, MI = 2, NI = 4;
  __shared__ __align__(16) bf16_t As[BM * LD];
  __shared__ __align__(16) bf16_t Bs[BN * LD];
  const int tid = threadIdx.x;
  const int lane = tid & 63, wid = tid >> 6;
  const int quad = lane >> 4, l16 = lane & 15;
  const int b = blockIdx.z;
  const bf16_t* B = hnT + (size_t)b * 1048576;
  const int m0 = blockIdx.y * BM, n0 = blockIdx.x * BN;
  const int wm0 = (wid >> 1) * 32, wn0 = (wid & 1) * 64;

  floatx4 acc[MI][NI];
#pragma unroll
  for (int i = 0; i < MI; ++i)
#pragma unroll
    for (int j = 0; j < NI; ++j) acc[i][j] = (floatx4){0.f, 0.f, 0.f, 0.f};

  const int arow = tid >> 2, akj = (tid & 3) << 3;
  for (int kt = 0; kt < 256; kt += BK) {
    {
      int r = arow;  // 0..63
      *(uint4*)&As[r * LD + akj] = *(const uint4*)&Astack[(size_t)(m0 + r) * 256 + kt + akj];
    }
#pragma unroll
    for (int p = 0; p < 2; ++p) {
      int r = p * 64 + arow;
      *(uint4*)&Bs[r * LD + akj] = *(const uint4*)&B[(size_t)(n0 + r) * 256 + kt + akj];
    }
    __syncthreads();
    bf16x8 af[MI], bfr[NI];
#pragma unroll
    for (int i = 0; i < MI; ++i) af[i] = *(const bf16x8*)&As[(wm0 + i * 16 + l16) * LD + quad * 8];
#pragma unroll
    for (int j = 0; j < NI; ++j) bfr[j] = *(const bf16x8*)&Bs[(wn0 + j * 16 + l16) * LD + quad * 8];
#pragma unroll
    for (int i = 0; i < MI; ++i)
#pragma unroll
      for (int j = 0; j < NI; ++j)
        acc[i][j] = __builtin_amdgcn_mfma_f32_16x16x32_bf16(af[i], bfr[j], acc[i][j], 0, 0, 0);
    __syncthreads();
  }

#pragma unroll
  for (int i = 0; i < MI; ++i) {
    int gmb = m0 + wm0 + i * 16 + quad * 4;
#pragma unroll
    for (int j = 0; j < NI; ++j) {
      int gn = n0 + wn0 + j * 16 + l16;
      float v[4];
#pragma unroll
      for (int r = 0; r < 4; ++r) v[r] = acc[i][j][r] + bqkv2[gmb + r];
      if (m0 < 512) {  // q/k: transposed bf16 store into qkT[b][n][512]
        ushort4 u = make_ushort4(f2bf(v[0]), f2bf(v[1]), f2bf(v[2]), f2bf(v[3]));
        *(ushort4*)&qkT[(size_t)b * 2097152 + (size_t)gn * 512 + gmb] = u;
      } else {  // W2 rows: natural store [o][n]
#pragma unroll
        for (int r = 0; r < 4; ++r)
          W2[(size_t)b * 1048576 + (size_t)(gmb - 512 + r) * 4096 + gn] = f2bf(v[r]);
      }
    }
  }
}

// ---------------- QK^T + exp + colsum, coalesced E^T store -----------------
__launch_bounds__(256)
__global__ void gemm_qk_exp(const bf16_t* __restrict__ qkT, unsigned short* __restrict__ EbfT,
                            float* __restrict__ psum) {
  constexpr int BM = 128, BN = 128, BK = 32, LD = BK + 8, MI = 4, NI = 4;
  constexpr int LDC = BM + 8;  // 136
  __shared__ __align__(16) char SMEM[BM * LDC * 2];  // 34816 B; aliases As+Bs
  bf16_t* As = (bf16_t*)SMEM;
  bf16_t* Bs = (bf16_t*)SMEM + BM * LD;
  unsigned short* Ct = (unsigned short*)SMEM;  // [BN][LDC], m-contiguous
  const int tid = threadIdx.x;
  const int lane = tid & 63, wid = tid >> 6;
  const int quad = lane >> 4, l16 = lane & 15;
  const int b = blockIdx.z;
  const bf16_t* A = qkT + (size_t)b * 2097152 + 256;  // k
  const bf16_t* B = qkT + (size_t)b * 2097152;        // q
  const int m0 = blockIdx.y * BM, n0 = blockIdx.x * BN;
  const int wm0 = (wid >> 1) * 64, wn0 = (wid & 1) * 64;

  floatx4 acc[MI][NI];
#pragma unroll
  for (int i = 0; i < MI; ++i)
#pragma unroll
    for (int j = 0; j < NI; ++j) acc[i][j] = (floatx4){0.f, 0.f, 0.f, 0.f};

  const int arow = tid >> 2, akj = (tid & 3) << 3;
  for (int kt = 0; kt < 256; kt += BK) {
#pragma unroll
    for (int p = 0; p < 2; ++p) {
      int r = p * 64 + arow;
      *(uint4*)&As[r * LD + akj] = *(const uint4*)&A[(size_t)(m0 + r) * 512 + kt + akj];
      *(uint4*)&Bs[r * LD + akj] = *(const uint4*)&B[(size_t)(n0 + r) * 512 + kt + akj];
    }
    __syncthreads();
    bf16x8 af[MI], bfr[NI];
#pragma unroll
    for (int i = 0; i < MI; ++i) af[i] = *(const bf16x8*)&As[(wm0 + i * 16 + l16) * LD + quad * 8];
#pragma unroll
    for (int j = 0; j < NI; ++j) bfr[j] = *(const bf16x8*)&Bs[(wn0 + j * 16 + l16) * LD + quad * 8];
#pragma unroll
    for (int i = 0; i < MI; ++i)
#pragma unroll
      for (int j = 0; j < NI; ++j)
        acc[i][j] = __builtin_amdgcn_mfma_f32_16x16x32_bf16(af[i], bfr[j], acc[i][j], 0, 0, 0);
    __syncthreads();
  }

  float csum[NI] = {0.f, 0.f, 0.f, 0.f};
#pragma unroll
  for (int i = 0; i < MI; ++i) {
    int ml = wm0 + i * 16 + quad * 4;
#pragma unroll
    for (int j = 0; j < NI; ++j) {
      int nl = wn0 + j * 16 + l16;
      float e[4];
#pragma unroll
      for (int r = 0; r < 4; ++r) e[r] = __expf(acc[i][j][r] * 0.0625f);
      csum[j] += (e[0] + e[1]) + (e[2] + e[3]);
      *(ushort4*)&Ct[nl * LDC + ml] = make_ushort4(f2bf(e[0]), f2bf(e[1]), f2bf(e[2]), f2bf(e[3]));
    }
  }
#pragma unroll
  for (int j = 0; j < NI; ++j) {
    csum[j] += __shfl_xor(csum[j], 16);
    csum[j] += __shfl_xor(csum[j], 32);
  }
  if (quad == 0) {
    int my = blockIdx.y * 2 + (wid >> 1);
#pragma unroll
    for (int j = 0; j < NI; ++j)
      psum[((size_t)b * 64 + my) * 4096 + n0 + wn0 + j * 16 + l16] = csum[j];
  }
  __syncthreads();
#pragma unroll
  for (int pass = 0; pass < 8; ++pass) {
    int row = pass * 16 + (tid >> 4);
    int mc = (tid & 15) * 8;
    uint4 v = *(uint4*)&Ct[row * LDC + mc];
    *(uint4*)&EbfT[(size_t)b * 16777216 + (size_t)(n0 + row) * 4096 + m0 + mc] = v;
  }
}

// ---------------- fused PV GEMM: rsum prologue + P^T write + direct out ----
// grid (128 n-tiles, 2 mb, 2 b), 256 threads. BM=128 (channels), BN=32, K=4096.
__launch_bounds__(256)
__global__ void gemm_pv_fused(const bf16_t* __restrict__ W2, const bf16_t* __restrict__ EbfT,
                              const float* __restrict__ psum, const float* __restrict__ bias2,
                              const float* __restrict__ x, float* __restrict__ out0,
                              float* __restrict__ attn) {
  constexpr int BK = 64, LDA = 72, LDB = 72;
  __shared__ __align__(16) bf16_t As[128 * LDA];  // 18432 B
  __shared__ __align__(16) bf16_t Bs[32 * LDB];   // 4608 B
  __shared__ float rs[32];
  __shared__ float sred[256];
  const int tid = threadIdx.x;
  const int lane = tid & 63, wid = tid >> 6;
  const int quad = lane >> 4, l16 = lane & 15;
  const int b = blockIdx.z, mb = blockIdx.y;
  const int n0 = blockIdx.x * 32;
  const size_t eb = (size_t)b * 16777216;

  // rsum prologue: 8 threads per n over 64 psum rows
  {
    int nl = tid & 31, rp = tid >> 5;
    float s = 0.f;
#pragma unroll
    for (int i = 0; i < 8; ++i) s += psum[((size_t)b * 64 + rp * 8 + i) * 4096 + n0 + nl];
    sred[tid] = s;
  }
  __syncthreads();
  if (tid < 32) {
    float s = 0.f;
#pragma unroll
    for (int i = 0; i < 8; ++i) s += sred[i * 32 + tid];
    rs[tid] = 1.f / s;
  }
  __syncthreads();

  const int wm0 = (wid >> 1) * 64, wn0 = (wid & 1) * 16;
  floatx4 acc[4];
#pragma unroll
  for (int i = 0; i < 4; ++i) acc[i] = (floatx4){0.f, 0.f, 0.f, 0.f};

  for (int kt = 0; kt < 4096; kt += BK) {
#pragma unroll
    for (int p = 0; p < 4; ++p) {
      int r = p * 32 + (tid >> 3);
      int kk = (tid & 7) * 8;
      *(uint4*)&As[r * LDA + kk] =
          *(const uint4*)&W2[(size_t)b * 1048576 + (size_t)(mb * 128 + r) * 4096 + kt + kk];
    }
    {
      int r = tid >> 3;  // 0..31
      int kk = (tid & 7) * 8;
      *(uint4*)&Bs[r * LDB + kk] = *(const uint4*)&EbfT[eb + (size_t)(n0 + r) * 4096 + kt + kk];
    }
    __syncthreads();
    // P^T write: this mb writes 32 of the 64 staged m-rows
    {
      int ml = mb * 32 + (tid >> 3);
      int n4 = (tid & 7) * 4;
      const unsigned short* Bu = (const unsigned short*)Bs;
      float4 o;
      o.x = bf2f(Bu[(n4 + 0) * LDB + ml]) * rs[n4 + 0];
      o.y = bf2f(Bu[(n4 + 1) * LDB + ml]) * rs[n4 + 1];
      o.z = bf2f(Bu[(n4 + 2) * LDB + ml]) * rs[n4 + 2];
      o.w = bf2f(Bu[(n4 + 3) * LDB + ml]) * rs[n4 + 3];
      *(float4*)&attn[eb + (size_t)(kt + ml) * 4096 + n0 + n4] = o;
    }
    bf16x8 af[2][4], bfr[2];
#pragma unroll
    for (int ks = 0; ks < 2; ++ks) {
      bfr[ks] = *(const bf16x8*)&Bs[(wn0 + l16) * LDB + ks * 32 + quad * 8];
#pragma unroll
      for (int i = 0; i < 4; ++i)
        af[ks][i] = *(const bf16x8*)&As[(wm0 + i * 16 + l16) * LDA + ks * 32 + quad * 8];
    }
#pragma unroll
    for (int ks = 0; ks < 2; ++ks)
#pragma unroll
      for (int i = 0; i < 4; ++i)
        acc[i] = __builtin_amdgcn_mfma_f32_16x16x32_bf16(af[ks][i], bfr[ks], acc[i], 0, 0, 0);
    __syncthreads();
  }

  const float* xb = x + (size_t)b * 1048576;
  float* ob = out0 + (size_t)b * 1048576;
  int gn = n0 + wn0 + l16;
  float cs = rs[wn0 + l16];
#pragma unroll
  for (int i = 0; i < 4; ++i) {
    int o = mb * 128 + wm0 + i * 16 + quad * 4;
#pragma unroll
    for (int r = 0; r < 4; ++r)
      ob[(size_t)(o + r) * 4096 + gn] =
          acc[i][r] * cs + bias2[o + r] + xb[(size_t)(o + r) * 4096 + gn];
  }
}

extern "C" void kernel_launch(void* const* d_in, const int* in_sizes, int n_in,
                              void* d_out, int out_size, void* d_ws, size_t ws_size,
                              hipStream_t stream) {
  const float* x = (const float*)d_in[0];
  const float* gamma = (const float*)d_in[1];
  const float* beta = (const float*)d_in[2];
  const float* wq = (const float*)d_in[3];
  const float* bq = (const float*)d_in[4];
  const float* wk = (const float*)d_in[5];
  const float* bk = (const float*)d_in[6];
  const float* wv = (const float*)d_in[7];
  const float* bv = (const float*)d_in[8];
  const float* wp = (const float*)d_in[9];
  const float* bp = (const float*)d_in[10];

  float* out0 = (float*)d_out;            // (2,256,4096)
  float* attn = (float*)d_out + 2097152;  // (2,4096,4096) = P^T fp32

  char* ws = (char*)d_ws;
  unsigned short* Astack = (unsigned short*)(ws + 0);      // 768x256 bf16 = 393216 B
  unsigned short* wpbf = (unsigned short*)(ws + 393216);   // 256x256 bf16
  unsigned short* wvT = (unsigned short*)(ws + 524288);    // 256x256 bf16
  float* bqkv2 = (float*)(ws + 655360);                    // 768
  float* bias2 = (float*)(ws + 658432);                    // 256
  float* gmean = (float*)(ws + 659456);                    // 64
  float* grstd = (float*)(ws + 659712);                    // 64
  float* psum = (float*)(ws + 1048576);                    // (2,64,4096) fp32
  unsigned short* hnT = (unsigned short*)(ws + 4194304);   // (2,4096,256) bf16
  unsigned short* qkT = (unsigned short*)(ws + 8388608);   // (2,4096,512) bf16
  unsigned short* W2 = (unsigned short*)(ws + 16777216);   // (2,256,4096) bf16
  unsigned short* EbfT = (unsigned short*)(ws + 20971520); // (2,4096,4096) bf16

  prep_kernel<<<853, 256, 0, stream>>>(wq, wk, wv, wp, bq, bk, bv, bp, x, Astack, wpbf, wvT,
                                       bqkv2, bias2, gmean, grstd);

  // wpv = wp·wv -> Astack rows 512-767 (A=wp_bf [o][c'], B=wvT [c''][c'])
  gemm_tn<64, 128><<<dim3(2, 4, 1), 256, 0, stream>>>((const bf16_t*)wpbf, (const bf16_t*)wvT, 256,
                                                      Astack + 131072, 256, 256);

  gn_apply_t_kernel<<<dim3(64, 4, 2), 256, 0, stream>>>(x, gamma, beta, gmean, grstd, hnT);

  // merged QKV + W2 GEMM
  gemm_qkvw<<<dim3(32, 12, 2), 256, 0, stream>>>((const bf16_t*)Astack, (const bf16_t*)hnT, bqkv2,
                                                 qkT, W2);

  gemm_qk_exp<<<dim3(32, 32, 2), 256, 0, stream>>>((const bf16_t*)qkT, EbfT, psum);

  gemm_pv_fused<<<dim3(128, 2, 2), 256, 0, stream>>>((const bf16_t*)W2, (const bf16_t*)EbfT, psum,
                                                     bias2, x, out0, attn);
}